// Round 16
// baseline (497.855 us; speedup 1.0000x reference)
//
#include <hip/hip_runtime.h>
#include <cstddef>
#include <cstdint>

static constexpr int BB = 4;
static constexpr int SS = 2048;
static constexpr int DD = 1024;
static constexpr int HH = 16;
static constexpr int HDIM = 64;
static constexpr int MROWS = BB * SS;          // 8192

typedef __attribute__((ext_vector_type(4))) float f32x4;
typedef __bf16 bf16x8 __attribute__((ext_vector_type(8)));
typedef __bf16 bf16x4 __attribute__((ext_vector_type(4)));

#define GLB_U32(p) ((const __attribute__((address_space(1))) uint32_t*)(p))
#define LDS_U32(p) ((__attribute__((address_space(3))) uint32_t*)(p))

__device__ __forceinline__ float fexp2(float x) {
#if __has_builtin(__builtin_amdgcn_exp2f)
    return __builtin_amdgcn_exp2f(x);
#else
    return exp2f(x);
#endif
}

// ---------------------------------------------------------------------------
// prep: fused input conversion + weight transposes (one launch).
// z < 4 : transpose W[z] [k][n] fp32 -> WT [n][k] bf16 (64x64 tiles, x/y grid)
// z == 4: convert x fp32 -> bf16 (256 flat blocks, 16 sweeps of 8 elem/thread)
// ---------------------------------------------------------------------------
__global__ __launch_bounds__(256) void prep(
    const float* __restrict__ x,
    const float* __restrict__ W0, const float* __restrict__ W1,
    const float* __restrict__ W2, const float* __restrict__ W3,
    __bf16* __restrict__ xb, __bf16* __restrict__ wt_base)
{
    const int t = threadIdx.x;

    if (blockIdx.z < 4) {
        const float* W = (blockIdx.z == 0) ? W0 : (blockIdx.z == 1) ? W1
                       : (blockIdx.z == 2) ? W2 : W3;
        __bf16* WT = wt_base + (size_t)blockIdx.z * 1048576;

        __shared__ float T[64][68];
        const int n0 = blockIdx.x * 64, k0 = blockIdx.y * 64;

#pragma unroll
        for (int it = 0; it < 4; ++it) {
            const int row = it * 16 + (t >> 4);
            const int col = (t & 15) * 4;
            float4 v = *reinterpret_cast<const float4*>(&W[(size_t)(k0 + row) * 1024 + n0 + col]);
            T[row][col + 0] = v.x; T[row][col + 1] = v.y;
            T[row][col + 2] = v.z; T[row][col + 3] = v.w;
        }
        __syncthreads();

#pragma unroll
        for (int it = 0; it < 2; ++it) {
            const int idx = it * 256 + t;
            const int n = idx >> 3, ch = idx & 7;
            bf16x8 v;
#pragma unroll
            for (int e = 0; e < 8; ++e) v[e] = (__bf16)T[ch * 8 + e][n];
            *reinterpret_cast<bf16x8*>(&WT[(size_t)(n0 + n) * 1024 + k0 + ch * 8]) = v;
        }
    } else {
        const int fb = blockIdx.y * 16 + blockIdx.x;        // 0..255
        size_t base = ((size_t)fb * 256 + t) * 8;
        for (int it = 0; it < 16; ++it) {
            const size_t i = base + (size_t)it * 524288;    // 256*256*8
            float4 a = *reinterpret_cast<const float4*>(x + i);
            float4 b = *reinterpret_cast<const float4*>(x + i + 4);
            bf16x8 v;
            v[0] = (__bf16)a.x; v[1] = (__bf16)a.y; v[2] = (__bf16)a.z; v[3] = (__bf16)a.w;
            v[4] = (__bf16)b.x; v[5] = (__bf16)b.y; v[6] = (__bf16)b.z; v[7] = (__bf16)b.w;
            *reinterpret_cast<bf16x8*>(xb + i) = v;
        }
    }
}

// ---------------------------------------------------------------------------
// Fused QKV GEMM: one launch, grid (64, 24); blockIdx.y>>3 selects Q/K/V.
// ---------------------------------------------------------------------------
__global__ __launch_bounds__(256) void gemm_qkv(
    const __bf16* __restrict__ xb, const __bf16* __restrict__ wt,
    const float* __restrict__ bq, const float* __restrict__ bk,
    const float* __restrict__ bv,
    __bf16* __restrict__ qb, __bf16* __restrict__ kb, __bf16* __restrict__ vtb)
{
    __shared__ __bf16 AB[2 * 128 * 32];        // At | Bt, reused by epilogue
    __bf16* At = AB;
    __bf16* Bt = AB + 4096;

    const int t = threadIdx.x;
    const int w = t >> 6, l = t & 63, l16 = l & 15, lg = l >> 4;
    const int m0 = blockIdx.x * 128;
    const int sel = blockIdx.y >> 3;
    const int n0 = (blockIdx.y & 7) * 128;
    const int wr = w >> 1, wc = w & 1;

    const __bf16* BT = wt + (size_t)sel * 1048576;
    const float* bias = (sel == 0) ? bq : (sel == 1) ? bk : bv;

    f32x4 acc[4][4] = {};

    for (int k0 = 0; k0 < 1024; k0 += 32) {
#pragma unroll
        for (int r = 0; r < 2; ++r) {
            const int cb = (w * 2 + r) * 64;
            const int ch = cb + l;
            const __bf16* srcA = xb + (size_t)(m0 + (ch >> 2)) * 1024 + k0 + (ch & 3) * 8;
            __builtin_amdgcn_global_load_lds(GLB_U32(srcA), LDS_U32(At + cb * 8), 16, 0, 0);
        }
#pragma unroll
        for (int r = 0; r < 2; ++r) {
            const int cb = (w * 2 + r) * 64;
            const int ch = cb + l;
            const __bf16* srcB = BT + (size_t)(n0 + (ch >> 2)) * 1024 + k0 + (ch & 3) * 8;
            __builtin_amdgcn_global_load_lds(GLB_U32(srcB), LDS_U32(Bt + cb * 8), 16, 0, 0);
        }
        __syncthreads();

        bf16x8 af[4], bf[4];
#pragma unroll
        for (int i = 0; i < 4; ++i) {
            af[i] = *reinterpret_cast<const bf16x8*>(At + (wr * 64 + i * 16 + l16) * 32 + lg * 8);
            bf[i] = *reinterpret_cast<const bf16x8*>(Bt + (wc * 64 + i * 16 + l16) * 32 + lg * 8);
        }
#pragma unroll
        for (int i = 0; i < 4; ++i)
#pragma unroll
            for (int j = 0; j < 4; ++j)
                acc[i][j] = __builtin_amdgcn_mfma_f32_16x16x32_bf16(af[i], bf[j], acc[i][j], 0, 0, 0);
        __syncthreads();
    }
    // last __syncthreads: AB free for epilogue reuse (wave-private regions)

    const float osc = (sel == 0) ? 0.18033688011112042f : 1.0f;

    if (sel < 2) {
        // Q/K: [b,h,s,hd] — contiguous hd (=n). Per j-slice: [64 m][16 n] LDS.
        __bf16* Et = AB + w * 2048;            // [64][24] bf16 (1536 els)
        __bf16* outp = (sel == 0) ? qb : kb;
#pragma unroll
        for (int j = 0; j < 4; ++j) {
            const float bvv = bias[n0 + wc * 64 + j * 16 + l16];
#pragma unroll
            for (int i = 0; i < 4; ++i)
#pragma unroll
                for (int r = 0; r < 4; ++r)
                    Et[(i * 16 + lg * 4 + r) * 24 + l16] =
                        (__bf16)((acc[i][j][r] + bvv) * osc);
#pragma unroll
            for (int it = 0; it < 2; ++it) {
                const int idx = it * 64 + l;
                const int ml = idx >> 1, ch = idx & 1;
                bf16x8 v = *(const bf16x8*)(Et + ml * 24 + ch * 8);
                const int M = m0 + wr * 64 + ml;
                const int N = n0 + wc * 64 + j * 16 + ch * 8;
                *(bf16x8*)(outp + (((size_t)(M >> 11) * HH + (N >> 6)) * SS
                                   + (M & 2047)) * HDIM + (N & 63)) = v;
            }
        }
    } else {
        // V^T: [b,h,hd,s] — contiguous s (=m). Per j-slice: [16 n][64 m] LDS.
        __bf16* Et = AB + w * 2048;            // [16][72] bf16 (1152 els)
#pragma unroll
        for (int j = 0; j < 4; ++j) {
            const float bvv = bias[n0 + wc * 64 + j * 16 + l16];
#pragma unroll
            for (int i = 0; i < 4; ++i)
#pragma unroll
                for (int r = 0; r < 4; ++r)
                    Et[l16 * 72 + i * 16 + lg * 4 + r] = (__bf16)(acc[i][j][r] + bvv);
#pragma unroll
            for (int it = 0; it < 2; ++it) {
                const int idx = it * 64 + l;
                const int row = idx >> 3, ch = idx & 7;
                bf16x8 v = *(const bf16x8*)(Et + row * 72 + ch * 8);
                const int N = n0 + wc * 64 + j * 16 + row;   // -> h, hd
                const int M = m0 + wr * 64 + ch * 8;         // -> b, s
                *(bf16x8*)(vtb + (((size_t)(M >> 11) * HH + (N >> 6)) * HDIM
                                  + (N & 63)) * SS + (M & 2047)) = v;
            }
        }
    }
}

// ---------------------------------------------------------------------------
// Output GEMM: out = attnb @ woT^T + bo  (fp32 out, [8192][1024]).
// ---------------------------------------------------------------------------
__global__ __launch_bounds__(256) void gemm_out(
    const __bf16* __restrict__ A, const __bf16* __restrict__ BT,
    const float* __restrict__ bias, float* __restrict__ C)
{
    __shared__ __bf16 AB[2 * 128 * 32];
    __bf16* At = AB;
    __bf16* Bt = AB + 4096;

    const int t = threadIdx.x;
    const int w = t >> 6, l = t & 63, l16 = l & 15, lg = l >> 4;
    const int m0 = blockIdx.x * 128, n0 = blockIdx.y * 128;
    const int wr = w >> 1, wc = w & 1;

    f32x4 acc[4][4] = {};

    for (int k0 = 0; k0 < 1024; k0 += 32) {
#pragma unroll
        for (int r = 0; r < 2; ++r) {
            const int cb = (w * 2 + r) * 64;
            const int ch = cb + l;
            const __bf16* srcA = A + (size_t)(m0 + (ch >> 2)) * 1024 + k0 + (ch & 3) * 8;
            __builtin_amdgcn_global_load_lds(GLB_U32(srcA), LDS_U32(At + cb * 8), 16, 0, 0);
        }
#pragma unroll
        for (int r = 0; r < 2; ++r) {
            const int cb = (w * 2 + r) * 64;
            const int ch = cb + l;
            const __bf16* srcB = BT + (size_t)(n0 + (ch >> 2)) * 1024 + k0 + (ch & 3) * 8;
            __builtin_amdgcn_global_load_lds(GLB_U32(srcB), LDS_U32(Bt + cb * 8), 16, 0, 0);
        }
        __syncthreads();

        bf16x8 af[4], bf[4];
#pragma unroll
        for (int i = 0; i < 4; ++i) {
            af[i] = *reinterpret_cast<const bf16x8*>(At + (wr * 64 + i * 16 + l16) * 32 + lg * 8);
            bf[i] = *reinterpret_cast<const bf16x8*>(Bt + (wc * 64 + i * 16 + l16) * 32 + lg * 8);
        }
#pragma unroll
        for (int i = 0; i < 4; ++i)
#pragma unroll
            for (int j = 0; j < 4; ++j)
                acc[i][j] = __builtin_amdgcn_mfma_f32_16x16x32_bf16(af[i], bf[j], acc[i][j], 0, 0, 0);
        __syncthreads();
    }

    float* Et = (float*)AB + w * 1024;         // [64][16] f32 = 4 KB per wave
#pragma unroll
    for (int j = 0; j < 4; ++j) {
        const float bvv = bias[n0 + wc * 64 + j * 16 + l16];
#pragma unroll
        for (int i = 0; i < 4; ++i)
#pragma unroll
            for (int r = 0; r < 4; ++r)
                Et[(i * 16 + lg * 4 + r) * 16 + l16] = acc[i][j][r] + bvv;
#pragma unroll
        for (int it = 0; it < 4; ++it) {
            const int idx = it * 64 + l;
            const int ml = idx >> 2, ch = idx & 3;
            float4 v = *(const float4*)(Et + ml * 16 + ch * 4);
            const int M = m0 + wr * 64 + ml;
            const int N = n0 + wc * 64 + j * 16 + ch * 4;
            *(float4*)(C + (size_t)M * 1024 + N) = v;
        }
    }
}

// ---------------------------------------------------------------------------
// LDS staging: 64x64 bf16 tile via global_load_lds, linear LDS dest,
// XOR swizzle applied on the GLOBAL source (both-sides-or-neither rule).
// ---------------------------------------------------------------------------
__device__ __forceinline__ void stage64x64(const __bf16* __restrict__ g, int rstride,
                                           __bf16* lds, int t)
{
#pragma unroll
    for (int it = 0; it < 2; ++it) {
        const int i = it * 256 + t;           // 16B chunk index, 0..511
        const int r = i >> 3, j = i & 7;
        const __bf16* src = g + (size_t)r * rstride + ((j ^ (r & 7)) << 3);
        __builtin_amdgcn_global_load_lds(GLB_U32(src), LDS_U32(lds + i * 8), 16, 0, 0);
    }
}

// read 16B at logical (row, elem col c0), c0 multiple of 8
__device__ __forceinline__ bf16x8 ldsF(const __bf16* buf, int row, int c0)
{
    return *(const bf16x8*)(buf + row * 64 + (((c0 >> 3) ^ (row & 7)) << 3));
}

// ---------------------------------------------------------------------------
// Fused attention, no-max softmax. Block = 4 waves, one 64-row q-tile.
// Grid = 2048 blocks (XCD-swizzled).
// Pass 1 (stats): K read DIRECTLY from global (L2-resident: 8 bh/XCD = 2MB),
//   NO LDS staging, NO barriers -> waves/blocks drift freely, compiler can
//   software-pipeline the loop (barriers previously forbade it).  Shrinks
//   the chip-wide store-less cold-start window.
// Pass 2 (identical to R15): K,V double-buffered in LDS; recompute QK^T ->
//   normalized weights (f32 NT stores) + normalized P (bf16) -> wave-private
//   swizzled LDS -> PV MFMA; loop bottom s_waitcnt vmcnt(4) + raw s_barrier
//   (staging loads drained, 4 NT stores stay in flight).
// Q pre-scaled by 0.125*log2(e) in its projection.
// ---------------------------------------------------------------------------
__global__ __launch_bounds__(256, 4) void attn_fused(
    const __bf16* __restrict__ Qg, const __bf16* __restrict__ Kg,
    const __bf16* __restrict__ VTg, float* __restrict__ Wout,
    __bf16* __restrict__ attnb)
{
    __shared__ __bf16 Ksh[2][64 * 64];
    __shared__ __bf16 Vsh[2][64 * 64];
    __shared__ __bf16 Psh[4][16 * 64];         // 2KB/wave: P swizzle + epi

    const int t = threadIdx.x, w = t >> 6, l = t & 63, l16 = l & 15, lg = l >> 4;

    int bid = (int)blockIdx.x;
    bid = (bid & 7) * 256 + (bid >> 3);        // bijective XCD swizzle (2048%8==0)
    const int qt = bid & 31, bh = bid >> 5;
    const int qr = qt * 64 + w * 16;

    const __bf16* Qp = Qg + ((size_t)bh * SS + qr) * HDIM;
    const __bf16* Kp = Kg + (size_t)bh * SS * HDIM;
    const __bf16* Vp = VTg + (size_t)bh * HDIM * SS;

    const bf16x8 aq0 = *(const bf16x8*)(Qp + l16 * 64 + lg * 8);
    const bf16x8 aq1 = *(const bf16x8*)(Qp + l16 * 64 + 32 + lg * 8);

    char* pbase = (char*)&Psh[w][0];

    // ---------------- pass 1: row-sum stats, direct-global K, no barriers --
    float ssum = 0.f;
    {
        const __bf16* kg = Kp + (size_t)(l16) * 64 + lg * 8;
        for (int kt = 0; kt < 32; ++kt) {
#pragma unroll
            for (int c4 = 0; c4 < 4; ++c4) {
                const __bf16* kr = kg + (size_t)(kt * 64 + c4 * 16) * 64;
                const bf16x8 b0 = *(const bf16x8*)(kr);
                const bf16x8 b1 = *(const bf16x8*)(kr + 32);
                f32x4 a = {0.f, 0.f, 0.f, 0.f};
                a = __builtin_amdgcn_mfma_f32_16x16x32_bf16(b0, aq0, a, 0, 0, 0);
                a = __builtin_amdgcn_mfma_f32_16x16x32_bf16(b1, aq1, a, 0, 0, 0);
                ssum += (fexp2(a[0]) + fexp2(a[1])) + (fexp2(a[2]) + fexp2(a[3]));
            }
        }
    }

    // issue pass-2 tile-0 staging, reduce sums while the loads fly
    stage64x64(Kp, 64, Ksh[0], t);
    stage64x64(Vp, SS, Vsh[0], t);

    ssum += __shfl_xor(ssum, 16);
    ssum += __shfl_xor(ssum, 32);
    const float linv = 1.0f / ssum;            // per-lane, row = l16

    __syncthreads();

    // ---------------- pass 2: weights + P + PV ----------------
    f32x4 o[4] = {};
    float* wbase = Wout + ((size_t)bh * SS + qr + l16) * SS;   // row = l16

    for (int kt = 0; kt < 32; ++kt) {
        if (kt < 31) {
            stage64x64(Kp + (kt + 1) * 4096, 64, Ksh[(kt + 1) & 1], t);
            stage64x64(Vp + (kt + 1) * 64, SS, Vsh[(kt + 1) & 1], t);
        }
        const __bf16* kb = Ksh[kt & 1];
        const __bf16* vb = Vsh[kt & 1];

#pragma unroll
        for (int c4 = 0; c4 < 4; ++c4) {
            const bf16x8 b0 = ldsF(kb, c4 * 16 + l16, lg * 8);
            const bf16x8 b1 = ldsF(kb, c4 * 16 + l16, 32 + lg * 8);
            f32x4 a = {0.f, 0.f, 0.f, 0.f};
            a = __builtin_amdgcn_mfma_f32_16x16x32_bf16(b0, aq0, a, 0, 0, 0);
            a = __builtin_amdgcn_mfma_f32_16x16x32_bf16(b1, aq1, a, 0, 0, 0);
            f32x4 pv;
            pv[0] = fexp2(a[0]) * linv; pv[1] = fexp2(a[1]) * linv;
            pv[2] = fexp2(a[2]) * linv; pv[3] = fexp2(a[3]) * linv;
            __builtin_nontemporal_store(pv,
                (f32x4*)(wbase + kt * 64 + c4 * 16 + lg * 4));
            bf16x4 pk;
            pk[0] = (__bf16)pv[0]; pk[1] = (__bf16)pv[1];
            pk[2] = (__bf16)pv[2]; pk[3] = (__bf16)pv[3];
            const int off = l16 * 128 + ((c4 * 32 + lg * 8) ^ ((l16 & 7) << 4));
            *(bf16x4*)(pbase + off) = pk;
        }
        asm volatile("s_waitcnt lgkmcnt(0)" ::: "memory");
        __builtin_amdgcn_sched_barrier(0);

        bf16x8 pa[2];
#pragma unroll
        for (int kc = 0; kc < 2; ++kc) {
            const int off = l16 * 128 + ((kc * 64 + lg * 16) ^ ((l16 & 7) << 4));
            pa[kc] = *(const bf16x8*)(pbase + off);
        }
#pragma unroll
        for (int nt = 0; nt < 4; ++nt) {
            const bf16x8 bv0 = ldsF(vb, nt * 16 + l16, lg * 8);
            const bf16x8 bv1 = ldsF(vb, nt * 16 + l16, 32 + lg * 8);
            o[nt] = __builtin_amdgcn_mfma_f32_16x16x32_bf16(pa[0], bv0, o[nt], 0, 0, 0);
            o[nt] = __builtin_amdgcn_mfma_f32_16x16x32_bf16(pa[1], bv1, o[nt], 0, 0, 0);
        }

        if (kt < 31) {
            // staging loads (issued before the 4 NT stores) are the oldest
            // vmcnt entries: outstanding<=4 proves LDS tiles landed while
            // the stores remain in flight across the barrier.
            asm volatile("s_waitcnt vmcnt(4)" ::: "memory");
            __builtin_amdgcn_s_barrier();
        }
    }

    // epilogue: O -> wave-private LDS transpose -> 16B coalesced stores.
    const int b = bh >> 4, h = bh & 15;
    __bf16* Pe = &Psh[w][0];                   // [16][64]
    asm volatile("s_waitcnt lgkmcnt(0)" ::: "memory");
    __builtin_amdgcn_sched_barrier(0);
#pragma unroll
    for (int nt = 0; nt < 4; ++nt)
#pragma unroll
        for (int r = 0; r < 4; ++r)
            Pe[(lg * 4 + r) * 64 + nt * 16 + l16] = (__bf16)o[nt][r];
    asm volatile("s_waitcnt lgkmcnt(0)" ::: "memory");
    __builtin_amdgcn_sched_barrier(0);
#pragma unroll
    for (int it = 0; it < 2; ++it) {
        const int idx = it * 64 + l;
        const int row = idx >> 3, ch = idx & 7;
        bf16x8 v = *(const bf16x8*)(Pe + row * 64 + ch * 8);
        *(bf16x8*)(attnb + ((size_t)b * SS + qr + row) * DD + h * 64 + ch * 8) = v;
    }
}

// ---------------------------------------------------------------------------
extern "C" void kernel_launch(void* const* d_in, const int* in_sizes, int n_in,
                              void* d_out, int out_size, void* d_ws, size_t ws_size,
                              hipStream_t stream)
{
    const float* x  = (const float*)d_in[0];
    const float* Wq = (const float*)d_in[1];
    const float* bq = (const float*)d_in[2];
    const float* Wk = (const float*)d_in[3];
    const float* bk = (const float*)d_in[4];
    const float* Wv = (const float*)d_in[5];
    const float* bv = (const float*)d_in[6];
    const float* Wo = (const float*)d_in[7];
    const float* bo = (const float*)d_in[8];

    float* out     = (float*)d_out;
    float* weights = out + (size_t)BB * SS * DD;

    __bf16* ws = (__bf16*)d_ws;
    const size_t NX = (size_t)MROWS * DD;   // 8,388,608
    __bf16* xb    = ws;
    __bf16* wtb   = xb + NX;                // wqT | wkT | wvT | woT
    __bf16* woT   = wtb + 3145728;
    __bf16* qb    = wtb + 4194304;
    __bf16* kb    = qb + NX;
    __bf16* vtb   = kb + NX;
    __bf16* attnb = vtb + NX;

    dim3 blk(256);

    prep<<<dim3(16, 16, 5), blk, 0, stream>>>(x, Wq, Wk, Wv, Wo, xb, wtb);

    gemm_qkv<<<dim3(64, 24), blk, 0, stream>>>(xb, wtb, bq, bk, bv, qb, kb, vtb);

    attn_fused<<<dim3(2048), blk, 0, stream>>>(qb, kb, vtb, weights, attnb);

    gemm_out<<<dim3(64, 8), blk, 0, stream>>>(attnb, woT, bo, out);
}

// Round 17
// 432.735 us; speedup vs baseline: 1.1505x; 1.1505x over previous
//
#include <hip/hip_runtime.h>
#include <cstddef>
#include <cstdint>

static constexpr int BB = 4;
static constexpr int SS = 2048;
static constexpr int DD = 1024;
static constexpr int HH = 16;
static constexpr int HDIM = 64;
static constexpr int MROWS = BB * SS;          // 8192

typedef __attribute__((ext_vector_type(4))) float f32x4;
typedef __bf16 bf16x8 __attribute__((ext_vector_type(8)));
typedef __bf16 bf16x4 __attribute__((ext_vector_type(4)));

#define GLB_U32(p) ((const __attribute__((address_space(1))) uint32_t*)(p))
#define LDS_U32(p) ((__attribute__((address_space(3))) uint32_t*)(p))

__device__ __forceinline__ float fexp2(float x) {
#if __has_builtin(__builtin_amdgcn_exp2f)
    return __builtin_amdgcn_exp2f(x);
#else
    return exp2f(x);
#endif
}

// ---------------------------------------------------------------------------
// prep: fused input conversion + weight transposes (one launch).
// z < 4 : transpose W[z] [k][n] fp32 -> WT [n][k] bf16 (64x64 tiles, x/y grid)
// z == 4: convert x fp32 -> bf16 (256 flat blocks, 16 sweeps of 8 elem/thread)
// ---------------------------------------------------------------------------
__global__ __launch_bounds__(256) void prep(
    const float* __restrict__ x,
    const float* __restrict__ W0, const float* __restrict__ W1,
    const float* __restrict__ W2, const float* __restrict__ W3,
    __bf16* __restrict__ xb, __bf16* __restrict__ wt_base)
{
    const int t = threadIdx.x;

    if (blockIdx.z < 4) {
        const float* W = (blockIdx.z == 0) ? W0 : (blockIdx.z == 1) ? W1
                       : (blockIdx.z == 2) ? W2 : W3;
        __bf16* WT = wt_base + (size_t)blockIdx.z * 1048576;

        __shared__ float T[64][68];
        const int n0 = blockIdx.x * 64, k0 = blockIdx.y * 64;

#pragma unroll
        for (int it = 0; it < 4; ++it) {
            const int row = it * 16 + (t >> 4);
            const int col = (t & 15) * 4;
            float4 v = *reinterpret_cast<const float4*>(&W[(size_t)(k0 + row) * 1024 + n0 + col]);
            T[row][col + 0] = v.x; T[row][col + 1] = v.y;
            T[row][col + 2] = v.z; T[row][col + 3] = v.w;
        }
        __syncthreads();

#pragma unroll
        for (int it = 0; it < 2; ++it) {
            const int idx = it * 256 + t;
            const int n = idx >> 3, ch = idx & 7;
            bf16x8 v;
#pragma unroll
            for (int e = 0; e < 8; ++e) v[e] = (__bf16)T[ch * 8 + e][n];
            *reinterpret_cast<bf16x8*>(&WT[(size_t)(n0 + n) * 1024 + k0 + ch * 8]) = v;
        }
    } else {
        const int fb = blockIdx.y * 16 + blockIdx.x;        // 0..255
        size_t base = ((size_t)fb * 256 + t) * 8;
        for (int it = 0; it < 16; ++it) {
            const size_t i = base + (size_t)it * 524288;    // 256*256*8
            float4 a = *reinterpret_cast<const float4*>(x + i);
            float4 b = *reinterpret_cast<const float4*>(x + i + 4);
            bf16x8 v;
            v[0] = (__bf16)a.x; v[1] = (__bf16)a.y; v[2] = (__bf16)a.z; v[3] = (__bf16)a.w;
            v[4] = (__bf16)b.x; v[5] = (__bf16)b.y; v[6] = (__bf16)b.z; v[7] = (__bf16)b.w;
            *reinterpret_cast<bf16x8*>(xb + i) = v;
        }
    }
}

// ---------------------------------------------------------------------------
// Fused QKV GEMM: one launch, grid (64, 24); blockIdx.y>>3 selects Q/K/V.
// ---------------------------------------------------------------------------
__global__ __launch_bounds__(256) void gemm_qkv(
    const __bf16* __restrict__ xb, const __bf16* __restrict__ wt,
    const float* __restrict__ bq, const float* __restrict__ bk,
    const float* __restrict__ bv,
    __bf16* __restrict__ qb, __bf16* __restrict__ kb, __bf16* __restrict__ vtb)
{
    __shared__ __bf16 AB[2 * 128 * 32];        // At | Bt, reused by epilogue
    __bf16* At = AB;
    __bf16* Bt = AB + 4096;

    const int t = threadIdx.x;
    const int w = t >> 6, l = t & 63, l16 = l & 15, lg = l >> 4;
    const int m0 = blockIdx.x * 128;
    const int sel = blockIdx.y >> 3;
    const int n0 = (blockIdx.y & 7) * 128;
    const int wr = w >> 1, wc = w & 1;

    const __bf16* BT = wt + (size_t)sel * 1048576;
    const float* bias = (sel == 0) ? bq : (sel == 1) ? bk : bv;

    f32x4 acc[4][4] = {};

    for (int k0 = 0; k0 < 1024; k0 += 32) {
#pragma unroll
        for (int r = 0; r < 2; ++r) {
            const int cb = (w * 2 + r) * 64;
            const int ch = cb + l;
            const __bf16* srcA = xb + (size_t)(m0 + (ch >> 2)) * 1024 + k0 + (ch & 3) * 8;
            __builtin_amdgcn_global_load_lds(GLB_U32(srcA), LDS_U32(At + cb * 8), 16, 0, 0);
        }
#pragma unroll
        for (int r = 0; r < 2; ++r) {
            const int cb = (w * 2 + r) * 64;
            const int ch = cb + l;
            const __bf16* srcB = BT + (size_t)(n0 + (ch >> 2)) * 1024 + k0 + (ch & 3) * 8;
            __builtin_amdgcn_global_load_lds(GLB_U32(srcB), LDS_U32(Bt + cb * 8), 16, 0, 0);
        }
        __syncthreads();

        bf16x8 af[4], bf[4];
#pragma unroll
        for (int i = 0; i < 4; ++i) {
            af[i] = *reinterpret_cast<const bf16x8*>(At + (wr * 64 + i * 16 + l16) * 32 + lg * 8);
            bf[i] = *reinterpret_cast<const bf16x8*>(Bt + (wc * 64 + i * 16 + l16) * 32 + lg * 8);
        }
#pragma unroll
        for (int i = 0; i < 4; ++i)
#pragma unroll
            for (int j = 0; j < 4; ++j)
                acc[i][j] = __builtin_amdgcn_mfma_f32_16x16x32_bf16(af[i], bf[j], acc[i][j], 0, 0, 0);
        __syncthreads();
    }
    // last __syncthreads: AB free for epilogue reuse (wave-private regions)

    const float osc = (sel == 0) ? 0.18033688011112042f : 1.0f;

    if (sel < 2) {
        // Q/K: [b,h,s,hd] — contiguous hd (=n). Per j-slice: [64 m][16 n] LDS.
        __bf16* Et = AB + w * 2048;            // [64][24] bf16 (1536 els)
        __bf16* outp = (sel == 0) ? qb : kb;
#pragma unroll
        for (int j = 0; j < 4; ++j) {
            const float bvv = bias[n0 + wc * 64 + j * 16 + l16];
#pragma unroll
            for (int i = 0; i < 4; ++i)
#pragma unroll
                for (int r = 0; r < 4; ++r)
                    Et[(i * 16 + lg * 4 + r) * 24 + l16] =
                        (__bf16)((acc[i][j][r] + bvv) * osc);
#pragma unroll
            for (int it = 0; it < 2; ++it) {
                const int idx = it * 64 + l;
                const int ml = idx >> 1, ch = idx & 1;
                bf16x8 v = *(const bf16x8*)(Et + ml * 24 + ch * 8);
                const int M = m0 + wr * 64 + ml;
                const int N = n0 + wc * 64 + j * 16 + ch * 8;
                *(bf16x8*)(outp + (((size_t)(M >> 11) * HH + (N >> 6)) * SS
                                   + (M & 2047)) * HDIM + (N & 63)) = v;
            }
        }
    } else {
        // V^T: [b,h,hd,s] — contiguous s (=m). Per j-slice: [16 n][64 m] LDS.
        __bf16* Et = AB + w * 2048;            // [16][72] bf16 (1152 els)
#pragma unroll
        for (int j = 0; j < 4; ++j) {
            const float bvv = bias[n0 + wc * 64 + j * 16 + l16];
#pragma unroll
            for (int i = 0; i < 4; ++i)
#pragma unroll
                for (int r = 0; r < 4; ++r)
                    Et[l16 * 72 + i * 16 + lg * 4 + r] = (__bf16)(acc[i][j][r] + bvv);
#pragma unroll
            for (int it = 0; it < 2; ++it) {
                const int idx = it * 64 + l;
                const int row = idx >> 3, ch = idx & 7;
                bf16x8 v = *(const bf16x8*)(Et + row * 72 + ch * 8);
                const int N = n0 + wc * 64 + j * 16 + row;   // -> h, hd
                const int M = m0 + wr * 64 + ch * 8;         // -> b, s
                *(bf16x8*)(vtb + (((size_t)(M >> 11) * HH + (N >> 6)) * HDIM
                                  + (N & 63)) * SS + (M & 2047)) = v;
            }
        }
    }
}

// ---------------------------------------------------------------------------
// Output GEMM: out = attnb @ woT^T + bo  (fp32 out, [8192][1024]).
// ---------------------------------------------------------------------------
__global__ __launch_bounds__(256) void gemm_out(
    const __bf16* __restrict__ A, const __bf16* __restrict__ BT,
    const float* __restrict__ bias, float* __restrict__ C)
{
    __shared__ __bf16 AB[2 * 128 * 32];
    __bf16* At = AB;
    __bf16* Bt = AB + 4096;

    const int t = threadIdx.x;
    const int w = t >> 6, l = t & 63, l16 = l & 15, lg = l >> 4;
    const int m0 = blockIdx.x * 128, n0 = blockIdx.y * 128;
    const int wr = w >> 1, wc = w & 1;

    f32x4 acc[4][4] = {};

    for (int k0 = 0; k0 < 1024; k0 += 32) {
#pragma unroll
        for (int r = 0; r < 2; ++r) {
            const int cb = (w * 2 + r) * 64;
            const int ch = cb + l;
            const __bf16* srcA = A + (size_t)(m0 + (ch >> 2)) * 1024 + k0 + (ch & 3) * 8;
            __builtin_amdgcn_global_load_lds(GLB_U32(srcA), LDS_U32(At + cb * 8), 16, 0, 0);
        }
#pragma unroll
        for (int r = 0; r < 2; ++r) {
            const int cb = (w * 2 + r) * 64;
            const int ch = cb + l;
            const __bf16* srcB = BT + (size_t)(n0 + (ch >> 2)) * 1024 + k0 + (ch & 3) * 8;
            __builtin_amdgcn_global_load_lds(GLB_U32(srcB), LDS_U32(Bt + cb * 8), 16, 0, 0);
        }
        __syncthreads();

        bf16x8 af[4], bf[4];
#pragma unroll
        for (int i = 0; i < 4; ++i) {
            af[i] = *reinterpret_cast<const bf16x8*>(At + (wr * 64 + i * 16 + l16) * 32 + lg * 8);
            bf[i] = *reinterpret_cast<const bf16x8*>(Bt + (wc * 64 + i * 16 + l16) * 32 + lg * 8);
        }
#pragma unroll
        for (int i = 0; i < 4; ++i)
#pragma unroll
            for (int j = 0; j < 4; ++j)
                acc[i][j] = __builtin_amdgcn_mfma_f32_16x16x32_bf16(af[i], bf[j], acc[i][j], 0, 0, 0);
        __syncthreads();
    }

    float* Et = (float*)AB + w * 1024;         // [64][16] f32 = 4 KB per wave
#pragma unroll
    for (int j = 0; j < 4; ++j) {
        const float bvv = bias[n0 + wc * 64 + j * 16 + l16];
#pragma unroll
        for (int i = 0; i < 4; ++i)
#pragma unroll
            for (int r = 0; r < 4; ++r)
                Et[(i * 16 + lg * 4 + r) * 16 + l16] = acc[i][j][r] + bvv;
#pragma unroll
        for (int it = 0; it < 4; ++it) {
            const int idx = it * 64 + l;
            const int ml = idx >> 2, ch = idx & 3;
            float4 v = *(const float4*)(Et + ml * 16 + ch * 4);
            const int M = m0 + wr * 64 + ml;
            const int N = n0 + wc * 64 + j * 16 + ch * 4;
            *(float4*)(C + (size_t)M * 1024 + N) = v;
        }
    }
}

// ---------------------------------------------------------------------------
// LDS staging: 64x64 bf16 tile via global_load_lds, linear LDS dest,
// XOR swizzle applied on the GLOBAL source (both-sides-or-neither rule).
// ---------------------------------------------------------------------------
__device__ __forceinline__ void stage64x64(const __bf16* __restrict__ g, int rstride,
                                           __bf16* lds, int t)
{
#pragma unroll
    for (int it = 0; it < 2; ++it) {
        const int i = it * 256 + t;           // 16B chunk index, 0..511
        const int r = i >> 3, j = i & 7;
        const __bf16* src = g + (size_t)r * rstride + ((j ^ (r & 7)) << 3);
        __builtin_amdgcn_global_load_lds(GLB_U32(src), LDS_U32(lds + i * 8), 16, 0, 0);
    }
}

// read 16B at logical (row, elem col c0), c0 multiple of 8
__device__ __forceinline__ bf16x8 ldsF(const __bf16* buf, int row, int c0)
{
    return *(const bf16x8*)(buf + row * 64 + (((c0 >> 3) ^ (row & 7)) << 3));
}

// ---------------------------------------------------------------------------
// Fused attention, no-max softmax. Block = 4 waves, one 64-row q-tile.
// Grid = 2048 blocks (XCD-swizzled).  R15 champion structure:
// - NONTEMPORAL weight stores (R14 A/B: NT = -57 us, protects L2 from the
//   1.07 GB write-once stream evicting K/V).
// - LDS-staged pass 1 (R16 A/B: direct-global = -64 us, staging provides
//   the latency pipelining).
// Pass 1 (stats): QK^T -> exp2 -> row-sum.  K-only double-buffered staging.
// Pass 2: recompute QK^T -> normalized weights (f32 NT stores) + normalized
//         P (bf16) -> wave-private swizzled LDS -> PV MFMA.
//         Loop bottom: s_waitcnt vmcnt(4) + raw s_barrier (staging loads,
//         issued before the 4 weight stores, proven drained by FIFO vmcnt;
//         stores stay in flight across the barrier).
// Q pre-scaled by 0.125*log2(e) in its projection.
// ---------------------------------------------------------------------------
__global__ __launch_bounds__(256, 4) void attn_fused(
    const __bf16* __restrict__ Qg, const __bf16* __restrict__ Kg,
    const __bf16* __restrict__ VTg, float* __restrict__ Wout,
    __bf16* __restrict__ attnb)
{
    __shared__ __bf16 Ksh[2][64 * 64];
    __shared__ __bf16 Vsh[2][64 * 64];
    __shared__ __bf16 Psh[4][16 * 64];         // 2KB/wave: P swizzle + epi

    const int t = threadIdx.x, w = t >> 6, l = t & 63, l16 = l & 15, lg = l >> 4;

    int bid = (int)blockIdx.x;
    bid = (bid & 7) * 256 + (bid >> 3);        // bijective XCD swizzle (2048%8==0)
    const int qt = bid & 31, bh = bid >> 5;
    const int qr = qt * 64 + w * 16;

    const __bf16* Qp = Qg + ((size_t)bh * SS + qr) * HDIM;
    const __bf16* Kp = Kg + (size_t)bh * SS * HDIM;
    const __bf16* Vp = VTg + (size_t)bh * HDIM * SS;

    const bf16x8 aq0 = *(const bf16x8*)(Qp + l16 * 64 + lg * 8);
    const bf16x8 aq1 = *(const bf16x8*)(Qp + l16 * 64 + 32 + lg * 8);

    char* pbase = (char*)&Psh[w][0];

    // ---------------- pass 1: row-sum stats only ----------------
    float ssum = 0.f;

    stage64x64(Kp, 64, Ksh[0], t);
    __syncthreads();

    for (int kt = 0; kt < 32; ++kt) {
        if (kt < 31) stage64x64(Kp + (kt + 1) * 4096, 64, Ksh[(kt + 1) & 1], t);
        const __bf16* kb = Ksh[kt & 1];

#pragma unroll
        for (int c4 = 0; c4 < 4; ++c4) {
            const bf16x8 b0 = ldsF(kb, c4 * 16 + l16, lg * 8);
            const bf16x8 b1 = ldsF(kb, c4 * 16 + l16, 32 + lg * 8);
            f32x4 a = {0.f, 0.f, 0.f, 0.f};
            a = __builtin_amdgcn_mfma_f32_16x16x32_bf16(b0, aq0, a, 0, 0, 0);
            a = __builtin_amdgcn_mfma_f32_16x16x32_bf16(b1, aq1, a, 0, 0, 0);
            ssum += (fexp2(a[0]) + fexp2(a[1])) + (fexp2(a[2]) + fexp2(a[3]));
        }
        __syncthreads();
    }

    // issue pass-2 tile-0 staging, reduce sums while the loads fly
    stage64x64(Kp, 64, Ksh[0], t);
    stage64x64(Vp, SS, Vsh[0], t);

    ssum += __shfl_xor(ssum, 16);
    ssum += __shfl_xor(ssum, 32);
    const float linv = 1.0f / ssum;            // per-lane, row = l16

    __syncthreads();

    // ---------------- pass 2: weights + P + PV ----------------
    f32x4 o[4] = {};
    float* wbase = Wout + ((size_t)bh * SS + qr + l16) * SS;   // row = l16

    for (int kt = 0; kt < 32; ++kt) {
        if (kt < 31) {
            stage64x64(Kp + (kt + 1) * 4096, 64, Ksh[(kt + 1) & 1], t);
            stage64x64(Vp + (kt + 1) * 64, SS, Vsh[(kt + 1) & 1], t);
        }
        const __bf16* kb = Ksh[kt & 1];
        const __bf16* vb = Vsh[kt & 1];

#pragma unroll
        for (int c4 = 0; c4 < 4; ++c4) {
            const bf16x8 b0 = ldsF(kb, c4 * 16 + l16, lg * 8);
            const bf16x8 b1 = ldsF(kb, c4 * 16 + l16, 32 + lg * 8);
            f32x4 a = {0.f, 0.f, 0.f, 0.f};
            a = __builtin_amdgcn_mfma_f32_16x16x32_bf16(b0, aq0, a, 0, 0, 0);
            a = __builtin_amdgcn_mfma_f32_16x16x32_bf16(b1, aq1, a, 0, 0, 0);
            f32x4 pv;
            pv[0] = fexp2(a[0]) * linv; pv[1] = fexp2(a[1]) * linv;
            pv[2] = fexp2(a[2]) * linv; pv[3] = fexp2(a[3]) * linv;
            __builtin_nontemporal_store(pv,
                (f32x4*)(wbase + kt * 64 + c4 * 16 + lg * 4));
            bf16x4 pk;
            pk[0] = (__bf16)pv[0]; pk[1] = (__bf16)pv[1];
            pk[2] = (__bf16)pv[2]; pk[3] = (__bf16)pv[3];
            const int off = l16 * 128 + ((c4 * 32 + lg * 8) ^ ((l16 & 7) << 4));
            *(bf16x4*)(pbase + off) = pk;
        }
        asm volatile("s_waitcnt lgkmcnt(0)" ::: "memory");
        __builtin_amdgcn_sched_barrier(0);

        bf16x8 pa[2];
#pragma unroll
        for (int kc = 0; kc < 2; ++kc) {
            const int off = l16 * 128 + ((kc * 64 + lg * 16) ^ ((l16 & 7) << 4));
            pa[kc] = *(const bf16x8*)(pbase + off);
        }
#pragma unroll
        for (int nt = 0; nt < 4; ++nt) {
            const bf16x8 bv0 = ldsF(vb, nt * 16 + l16, lg * 8);
            const bf16x8 bv1 = ldsF(vb, nt * 16 + l16, 32 + lg * 8);
            o[nt] = __builtin_amdgcn_mfma_f32_16x16x32_bf16(pa[0], bv0, o[nt], 0, 0, 0);
            o[nt] = __builtin_amdgcn_mfma_f32_16x16x32_bf16(pa[1], bv1, o[nt], 0, 0, 0);
        }

        if (kt < 31) {
            // staging loads (issued before the 4 NT stores) are the oldest
            // vmcnt entries: outstanding<=4 proves LDS tiles landed while
            // the stores remain in flight across the barrier.
            asm volatile("s_waitcnt vmcnt(4)" ::: "memory");
            __builtin_amdgcn_s_barrier();
        }
    }

    // epilogue: O -> wave-private LDS transpose -> 16B coalesced stores.
    const int b = bh >> 4, h = bh & 15;
    __bf16* Pe = &Psh[w][0];                   // [16][64]
    asm volatile("s_waitcnt lgkmcnt(0)" ::: "memory");
    __builtin_amdgcn_sched_barrier(0);
#pragma unroll
    for (int nt = 0; nt < 4; ++nt)
#pragma unroll
        for (int r = 0; r < 4; ++r)
            Pe[(lg * 4 + r) * 64 + nt * 16 + l16] = (__bf16)o[nt][r];
    asm volatile("s_waitcnt lgkmcnt(0)" ::: "memory");
    __builtin_amdgcn_sched_barrier(0);
#pragma unroll
    for (int it = 0; it < 2; ++it) {
        const int idx = it * 64 + l;
        const int row = idx >> 3, ch = idx & 7;
        bf16x8 v = *(const bf16x8*)(Pe + row * 64 + ch * 8);
        *(bf16x8*)(attnb + ((size_t)b * SS + qr + row) * DD + h * 64 + ch * 8) = v;
    }
}

// ---------------------------------------------------------------------------
extern "C" void kernel_launch(void* const* d_in, const int* in_sizes, int n_in,
                              void* d_out, int out_size, void* d_ws, size_t ws_size,
                              hipStream_t stream)
{
    const float* x  = (const float*)d_in[0];
    const float* Wq = (const float*)d_in[1];
    const float* bq = (const float*)d_in[2];
    const float* Wk = (const float*)d_in[3];
    const float* bk = (const float*)d_in[4];
    const float* Wv = (const float*)d_in[5];
    const float* bv = (const float*)d_in[6];
    const float* Wo = (const float*)d_in[7];
    const float* bo = (const float*)d_in[8];

    float* out     = (float*)d_out;
    float* weights = out + (size_t)BB * SS * DD;

    __bf16* ws = (__bf16*)d_ws;
    const size_t NX = (size_t)MROWS * DD;   // 8,388,608
    __bf16* xb    = ws;
    __bf16* wtb   = xb + NX;                // wqT | wkT | wvT | woT
    __bf16* woT   = wtb + 3145728;
    __bf16* qb    = wtb + 4194304;
    __bf16* kb    = qb + NX;
    __bf16* vtb   = kb + NX;
    __bf16* attnb = vtb + NX;

    dim3 blk(256);

    prep<<<dim3(16, 16, 5), blk, 0, stream>>>(x, Wq, Wk, Wv, Wo, xb, wtb);

    gemm_qkv<<<dim3(64, 24), blk, 0, stream>>>(xb, wtb, bq, bk, bv, qb, kb, vtb);

    attn_fused<<<dim3(2048), blk, 0, stream>>>(qb, kb, vtb, weights, attnb);

    gemm_out<<<dim3(64, 8), blk, 0, stream>>>(attnb, woT, bo, out);
}